// Round 10
// baseline (146.736 us; speedup 1.0000x reference)
//
#include <hip/hip_runtime.h>
#include <hip/hip_cooperative_groups.h>
#include <math.h>

namespace cg = cooperative_groups;

#define Bb 4
#define Cc 256
#define Hh 128
#define Ww 128
#define HW (Hh * Ww)
#define Kk 9

typedef float f32x4 __attribute__((ext_vector_type(4)));

// ---------------------------------------------------------------------------
// Fused kernel: phase 1 = proj (R6 winner verbatim), grid-sync, phase 2 =
// sample (R6 math, reshaped to 256 px/block x 4 tap-groups).
// grid = 256 blocks x 1024 threads = 1 block/CU, guaranteed co-resident
// (cooperative launch). LDS: 73,728 B proj reduction buffer, re-aliased
// as the 4 KB sample partial buffer after the grid sync.
// ---------------------------------------------------------------------------
__global__ __launch_bounds__(1024, 4) void fused_kernel(const float* __restrict__ x,
                                                        const float* __restrict__ w,
                                                        const float* __restrict__ off,
                                                        const float* __restrict__ bias,
                                                        float* __restrict__ D,
                                                        float* __restrict__ out) {
    const int tid   = threadIdx.x;
    const int lane  = tid & 63;
    const int wv    = tid >> 6;            // 0..15
    const int bid   = blockIdx.x;          // 0..255
    const int b     = bid >> 6;            // 64 blocks per batch image
    const int pbase = (bid & 63) << 8;     // 256 pixels per block

    __shared__ f32x4 red[8][64][Kk];       // 73,728 B (phase 1); aliased in phase 2

    // ======================= Phase 1: projection =======================
    {
        const int p4 = pbase + lane * 4;
        const int cu = __builtin_amdgcn_readfirstlane(wv);
        const float* __restrict__ wp = w + cu * 16 * Kk;
        const float* __restrict__ xp = x + (size_t)(b * Cc + cu * 16) * HW + p4;

        f32x4 acc[Kk];
#pragma unroll
        for (int k = 0; k < Kk; ++k) acc[k] = (f32x4)(0.f);

#pragma unroll 4
        for (int ci = 0; ci < 16; ++ci) {
            const f32x4 xv = *reinterpret_cast<const f32x4*>(xp + (size_t)ci * HW);
#pragma unroll
            for (int k = 0; k < Kk; ++k) {
                const float wk = wp[ci * Kk + k];
                acc[k] = __builtin_elementwise_fma(xv, (f32x4)(wk), acc[k]);
            }
        }

        if (wv < 8) {
#pragma unroll
            for (int k = 0; k < Kk; ++k) red[wv][lane][k] = acc[k];
        }
        __syncthreads();
        if (wv >= 8) {
#pragma unroll
            for (int k = 0; k < Kk; ++k) red[wv - 8][lane][k] += acc[k];
        }
        __syncthreads();

        const float* __restrict__ redf = (const float*)red;
        for (int idx = tid; idx < 256 * Kk; idx += 1024) {
            const int k  = idx >> 8;
            const int px = idx & 255;
            const int base = (px >> 2) * (Kk * 4) + k * 4 + (px & 3);
            float s = 0.f;
#pragma unroll
            for (int g = 0; g < 8; ++g) s += redf[g * (64 * Kk * 4) + base];
            D[(b * Kk + k) * HW + pbase + px] = s;
        }
    }

    // =================== grid-wide barrier (D complete) ===================
    cg::this_grid().sync();

    // ======================= Phase 2: sampling =========================
    {
        const int px = tid & 255;          // pixel within this block's tile
        const int g  = tid >> 8;           // 0..3, tap group (wave-uniform)
        const int p  = pbase + px;
        const int h  = p >> 7;
        const int w_ = p & (Ww - 1);

        const float* __restrict__ offb = off + (size_t)b * (2 * Kk) * HW + p;
        const float* __restrict__ Db   = D + (size_t)b * Kk * HW;

        float s = 0.f;

#define TAP(K)                                                                 \
    do {                                                                       \
        constexpr int kk = (K);                                                \
        constexpr int ky = kk / 3, kx = kk % 3;                                \
        const float dy = offb[(size_t)(2 * kk) * HW];                          \
        const float dx = offb[(size_t)(2 * kk + 1) * HW];                      \
        const float y  = (float)(h - 1 + ky) + dy;                             \
        const float xq = (float)(w_ - 1 + kx) + dx;                            \
        const float y0f = floorf(y);                                           \
        const float x0f = floorf(xq);                                          \
        const float wy  = y - y0f;                                             \
        const float wx  = xq - x0f;                                            \
        const int y0 = (int)y0f;                                               \
        const int x0 = (int)x0f;                                               \
        const float* __restrict__ Dk = Db + kk * HW;                           \
        {                                                                      \
            const int yy = y0, xx = x0;                                        \
            const bool valid = (yy >= 0) & (yy < Hh) & (xx >= 0) & (xx < Ww);  \
            const int yi = min(max(yy, 0), Hh - 1);                            \
            const int xi = min(max(xx, 0), Ww - 1);                            \
            const float v = Dk[yi * Ww + xi];                                  \
            s += valid ? (1.f - wy) * (1.f - wx) * v : 0.f;                    \
        }                                                                      \
        {                                                                      \
            const int yy = y0, xx = x0 + 1;                                    \
            const bool valid = (yy >= 0) & (yy < Hh) & (xx >= 0) & (xx < Ww);  \
            const int yi = min(max(yy, 0), Hh - 1);                            \
            const int xi = min(max(xx, 0), Ww - 1);                            \
            const float v = Dk[yi * Ww + xi];                                  \
            s += valid ? (1.f - wy) * wx * v : 0.f;                            \
        }                                                                      \
        {                                                                      \
            const int yy = y0 + 1, xx = x0;                                    \
            const bool valid = (yy >= 0) & (yy < Hh) & (xx >= 0) & (xx < Ww);  \
            const int yi = min(max(yy, 0), Hh - 1);                            \
            const int xi = min(max(xx, 0), Ww - 1);                            \
            const float v = Dk[yi * Ww + xi];                                  \
            s += valid ? wy * (1.f - wx) * v : 0.f;                            \
        }                                                                      \
        {                                                                      \
            const int yy = y0 + 1, xx = x0 + 1;                                \
            const bool valid = (yy >= 0) & (yy < Hh) & (xx >= 0) & (xx < Ww);  \
            const int yi = min(max(yy, 0), Hh - 1);                            \
            const int xi = min(max(xx, 0), Ww - 1);                            \
            const float v = Dk[yi * Ww + xi];                                  \
            s += valid ? wy * wx * v : 0.f;                                    \
        }                                                                      \
    } while (0)

        if (g == 0) {
            TAP(0); TAP(4); TAP(8);
        } else if (g == 1) {
            TAP(1); TAP(5);
        } else if (g == 2) {
            TAP(2); TAP(6);
        } else {
            TAP(3); TAP(7);
        }
#undef TAP

        // Alias the proj LDS buffer for the 4-way partial reduction.
        float* __restrict__ part = (float*)red;   // part[g*256 + px]
        part[g * 256 + px] = s;
        __syncthreads();

        if (tid < 256) {
            const float t = part[tid] + part[256 + tid] + part[512 + tid] +
                            part[768 + tid] + bias[0];
            out[(b << 14) + pbase + tid] = 1.f / (1.f + expf(-t));
        }
    }
}

extern "C" void kernel_launch(void* const* d_in, const int* in_sizes, int n_in,
                              void* d_out, int out_size, void* d_ws, size_t ws_size,
                              hipStream_t stream) {
    const float* x    = (const float*)d_in[0];  // [4,256,128,128]
    const float* off  = (const float*)d_in[1];  // [4,18,128,128]
    const float* w    = (const float*)d_in[2];  // [1,256,3,3]
    const float* bias = (const float*)d_in[3];  // [1]
    float* out        = (float*)d_out;          // [4,1,128,128]

    float* D = (float*)d_ws;  // [4][9][16384] f32 = 2.25 MB scratch

    void* args[] = {(void*)&x, (void*)&w, (void*)&off, (void*)&bias,
                    (void*)&D, (void*)&out};
    hipLaunchCooperativeKernel((const void*)fused_kernel, dim3(256), dim3(1024),
                               args, 0, stream);
}